// Round 1
// 1261.303 us; speedup vs baseline: 1.0433x; 1.0433x over previous
//
#include <hip/hip_runtime.h>
#include <hip/hip_bf16.h>

typedef __bf16 bf16x8 __attribute__((ext_vector_type(8)));
typedef float f32x4 __attribute__((ext_vector_type(4)));

#define S_LEN 4096
#define EMB   512
#define NHEAD 8
#define HDIM  64
#define NBAT  2
#define NROW  (NBAT * S_LEN)   // 8192

static __device__ __forceinline__ f32x4 mfma16x16(bf16x8 a, bf16x8 b, f32x4 c) {
    return __builtin_amdgcn_mfma_f32_16x16x32_bf16(a, b, c, 0, 0, 0);
}

// ---------------- convert fp32 -> bf16 ----------------
__global__ __launch_bounds__(256) void convert_kernel(
    const float* __restrict__ x, const float* __restrict__ Wq,
    const float* __restrict__ Wk, const float* __restrict__ Wv,
    const float* __restrict__ Wo,
    __hip_bfloat16* __restrict__ xb, __hip_bfloat16* __restrict__ wqkv,
    __hip_bfloat16* __restrict__ wob)
{
    const int NX = NROW * EMB;     // 4194304
    const int NW = EMB * EMB;      // 262144 = 2^18
    int i = blockIdx.x * 256 + threadIdx.x;
    if (i < NX) { xb[i] = __float2bfloat16(x[i]); return; }
    int j = i - NX;
    if (j < 3 * NW) {
        int p = j >> 18, r = j & (NW - 1);
        const float* src = (p == 0) ? Wq : (p == 1) ? Wk : Wv;
        wqkv[j] = __float2bfloat16(src[r]);
    } else if (j < 4 * NW) {
        int r = j - 3 * NW;
        wob[r] = __float2bfloat16(Wo[r]);
    }
}

// ---------------- shared GEMM mainloop ----------------
// C[128x64] tile = A[128xK] * B[64xK]^T, A/B bf16 row-major along K (K=512).
// Batched loads + 1-step register prefetch: loads for k0+32 issue right after
// the second barrier, so they overlap the MFMA phase instead of being exposed.
__device__ __forceinline__ void gemm_core(
    const __hip_bfloat16* __restrict__ A, const __hip_bfloat16* __restrict__ Bw,
    int mbase, int nbase,
    __hip_bfloat16* As, __hip_bfloat16* Bs, f32x4 acc[2][4])
{
    const int tid = threadIdx.x;
    const int w = tid >> 6, lane = tid & 63, l = lane & 15, quad = lane >> 4;
    const f32x4 zero = {0.f, 0.f, 0.f, 0.f};
#pragma unroll
    for (int mb = 0; mb < 2; mb++)
#pragma unroll
        for (int nb = 0; nb < 4; nb++) acc[mb][nb] = zero;

    const int r0 = tid >> 2, kc = tid & 3;
    const __hip_bfloat16* pa0 = A + (size_t)(mbase + r0) * EMB + kc * 8;
    const __hip_bfloat16* pa1 = pa0 + (size_t)64 * EMB;
    const __hip_bfloat16* pb  = Bw + (size_t)(nbase + r0) * EMB + kc * 8;

    uint4 va0 = *(const uint4*)pa0;
    uint4 va1 = *(const uint4*)pa1;
    uint4 vb  = *(const uint4*)pb;

    for (int k0 = 0; k0 < EMB; k0 += 32) {
        __syncthreads();
        *(uint4*)(As + r0 * 40 + kc * 8)        = va0;
        *(uint4*)(As + (r0 + 64) * 40 + kc * 8) = va1;
        *(uint4*)(Bs + r0 * 40 + kc * 8)        = vb;
        __syncthreads();
        if (k0 + 32 < EMB) {
            va0 = *(const uint4*)(pa0 + k0 + 32);
            va1 = *(const uint4*)(pa1 + k0 + 32);
            vb  = *(const uint4*)(pb  + k0 + 32);
        }
        bf16x8 af[2], bfr[4];
#pragma unroll
        for (int mb = 0; mb < 2; mb++)
            af[mb] = *(const bf16x8*)(As + (w * 32 + mb * 16 + l) * 40 + quad * 8);
#pragma unroll
        for (int nb = 0; nb < 4; nb++)
            bfr[nb] = *(const bf16x8*)(Bs + (nb * 16 + l) * 40 + quad * 8);
        __builtin_amdgcn_s_setprio(1);
#pragma unroll
        for (int mb = 0; mb < 2; mb++)
#pragma unroll
            for (int nb = 0; nb < 4; nb++)
                acc[mb][nb] = mfma16x16(af[mb], bfr[nb], acc[mb][nb]);
        __builtin_amdgcn_s_setprio(0);
    }
}

// ---------------- QKV projection ----------------
__global__ __launch_bounds__(256, 4) void qkv_gemm(
    const __hip_bfloat16* __restrict__ xb, const __hip_bfloat16* __restrict__ wqkv,
    const float* __restrict__ bq, const float* __restrict__ bk, const float* __restrict__ bv,
    __hip_bfloat16* __restrict__ Qh, __hip_bfloat16* __restrict__ Kh,
    __hip_bfloat16* __restrict__ Vt)
{
    __shared__ __align__(16) __hip_bfloat16 As[128 * 40];
    __shared__ __align__(16) __hip_bfloat16 Bs[64 * 40];
    const int mbase = blockIdx.x * 128, nbase = blockIdx.y * 64;
    f32x4 acc[2][4];
    gemm_core(xb, wqkv, mbase, nbase, As, Bs, acc);

    const int tid = threadIdx.x;
    const int w = tid >> 6, lane = tid & 63, l = lane & 15, quad = lane >> 4;
    const int p = nbase >> 9;  // uniform per block: 0=Q,1=K,2=V
    const float* bias = (p == 0) ? bq : (p == 1) ? bk : bv;
    __hip_bfloat16* dst = (p == 0) ? Qh : (p == 1) ? Kh : Vt;
#pragma unroll
    for (int mb = 0; mb < 2; mb++)
#pragma unroll
        for (int nb = 0; nb < 4; nb++)
#pragma unroll
            for (int r = 0; r < 4; r++) {
                int m = mbase + w * 32 + mb * 16 + quad * 4 + r;
                int n = nbase + nb * 16 + l;
                int o = n & 511;
                float v = acc[mb][nb][r] + bias[o];
                int b = m >> 12, s = m & 4095, hh = o >> 6, d = o & 63;
                size_t idx = (p == 2)
                    ? ((size_t)((hh * 2 + b) * 64 + d)) * 4096 + s
                    : ((size_t)((hh * 2 + b) * 4096 + s)) * 64 + d;
                dst[idx] = __float2bfloat16(v);
            }
}

// ---------------- flash attention ----------------
// Grid (H, qt): linear block id = h + 8*qt, so blkid%8 == h -> each head's
// 2MB K/V working set maps to one XCD's L2 under round-robin dispatch.
// Per kt iter: batched reg-prefetch of K/V (8x uint4) and bias/mask (16+16
// dwords) issued one iteration ahead, right after the second barrier, so the
// HBM latency hides under the MFMA/softmax compute of the current iteration.
__global__ __launch_bounds__(256, 2) void attn_kernel(
    const __hip_bfloat16* __restrict__ Qh, const __hip_bfloat16* __restrict__ Kh,
    const __hip_bfloat16* __restrict__ Vt,
    const float* __restrict__ bias, const int* __restrict__ mask,
    __hip_bfloat16* __restrict__ Om)
{
    const int h = blockIdx.x, qt = blockIdx.y;
    const int tid = threadIdx.x;
    const int w = tid >> 6, lane = tid & 63, l = lane & 15, quad = lane >> 4;
    const int q0 = qt * 64;
    const float CS = 0.18033688011112042f;  // (1/8) * log2(e)

    __shared__ __align__(16) __hip_bfloat16 Ks[2][64 * 72];
    __shared__ __align__(16) __hip_bfloat16 Vs[2][64 * 72];
    __shared__ __align__(16) __hip_bfloat16 Ps[64 * 72];

    // Q fragments (A-layout): row = q0 + w*16 + l, k = ks*32 + quad*8 + j
    bf16x8 qf[2][2];
#pragma unroll
    for (int b = 0; b < 2; b++) {
        const __hip_bfloat16* qp =
            Qh + ((size_t)((h * 2 + b) * 4096 + q0 + w * 16 + l)) * 64;
        qf[b][0] = *(const bf16x8*)(qp + quad * 8);
        qf[b][1] = *(const bf16x8*)(qp + 32 + quad * 8);
    }

    f32x4 oacc[2][4];
    float mst[2][4], lst[2][4];
    const f32x4 zero = {0.f, 0.f, 0.f, 0.f};
#pragma unroll
    for (int b = 0; b < 2; b++) {
#pragma unroll
        for (int nb = 0; nb < 4; nb++) oacc[b][nb] = zero;
#pragma unroll
        for (int r = 0; r < 4; r++) { mst[b][r] = -__builtin_inff(); lst[b][r] = 0.f; }
    }

    // Staging descriptors: 8 chunks/thread. Tile id t = j>>1 (compile-time):
    // t0=K.b0 t1=K.b1 t2=V.b0 t3=V.b1; row = (j&1)*32 + tid/8, ch = tid&7.
    const __hip_bfloat16* kvsrc[8];
    __hip_bfloat16* kvdst[8];
#pragma unroll
    for (int j = 0; j < 8; j++) {
        int c = j * 256 + tid;
        int t = c >> 9, b = t & 1, isV = t >> 1;
        int cc = c & 511, row = cc >> 3, ch = cc & 7;
        if (isV) {
            kvsrc[j] = Vt + ((size_t)((h * 2 + b) * 64 + row)) * 4096 + ch * 8;
            kvdst[j] = Vs[b] + row * 72 + ch * 8;
        } else {
            kvsrc[j] = Kh + ((size_t)((h * 2 + b) * 4096 + row)) * 64 + ch * 8;
            kvdst[j] = Ks[b] + row * 72 + ch * 8;
        }
    }
    const float* bptr[4];
    const int*   mptr[4];
#pragma unroll
    for (int r = 0; r < 4; r++) {
        int qq = q0 + w * 16 + quad * 4 + r;
        bptr[r] = bias + (size_t)h * S_LEN * S_LEN + (size_t)qq * S_LEN + l;
        mptr[r] = mask + (size_t)qq * S_LEN + l;
    }

    // ---- prologue: batched prefetch for kt = 0 ----
    uint4 kvbuf[8];
    float bb[4][4];
    int   mm[4][4];
#pragma unroll
    for (int j = 0; j < 8; j++) {
        kvbuf[j] = *(const uint4*)kvsrc[j];
        kvsrc[j] += (j >> 2) ? 64 : 64 * 64;   // V step : K step (k0 += 64)
    }
#pragma unroll
    for (int nb = 0; nb < 4; nb++)
#pragma unroll
        for (int r = 0; r < 4; r++) {
            bb[nb][r] = bptr[r][nb * 16];
            mm[nb][r] = mptr[r][nb * 16];
        }
#pragma unroll
    for (int r = 0; r < 4; r++) { bptr[r] += 64; mptr[r] += 64; }

    for (int kt = 0; kt < 64; kt++) {
        __syncthreads();  // prev-iter LDS readers done (+vmcnt drain = our wait)
#pragma unroll
        for (int j = 0; j < 8; j++) *(uint4*)kvdst[j] = kvbuf[j];
        // consume bias/mask regs before they get reloaded
        float bor[4][4];
#pragma unroll
        for (int nb = 0; nb < 4; nb++)
#pragma unroll
            for (int r = 0; r < 4; r++)
                bor[nb][r] = mm[nb][r] ? bb[nb][r] : -1e30f;
        __syncthreads();

        // ---- issue next-iter prefetch; stays in flight through compute ----
        if (kt < 63) {
#pragma unroll
            for (int j = 0; j < 8; j++) {
                kvbuf[j] = *(const uint4*)kvsrc[j];
                kvsrc[j] += (j >> 2) ? 64 : 64 * 64;
            }
#pragma unroll
            for (int nb = 0; nb < 4; nb++)
#pragma unroll
                for (int r = 0; r < 4; r++) {
                    bb[nb][r] = bptr[r][nb * 16];
                    mm[nb][r] = mptr[r][nb * 16];
                }
#pragma unroll
            for (int r = 0; r < 4; r++) { bptr[r] += 64; mptr[r] += 64; }
        }

#pragma unroll
        for (int b = 0; b < 2; b++) {
            // S = Q K^T
            f32x4 sc[4] = {zero, zero, zero, zero};
            __builtin_amdgcn_s_setprio(1);
#pragma unroll
            for (int ks = 0; ks < 2; ks++)
#pragma unroll
                for (int nb = 0; nb < 4; nb++) {
                    bf16x8 kf = *(const bf16x8*)(Ks[b] + (nb * 16 + l) * 72 + ks * 32 + quad * 8);
                    sc[nb] = mfma16x16(qf[b][ks], kf, sc[nb]);
                }
            __builtin_amdgcn_s_setprio(0);
            // masked-bias add, scale, online softmax (exp2 domain)
            float xv[4][4], rmax[4];
#pragma unroll
            for (int r = 0; r < 4; r++) rmax[r] = -__builtin_inff();
#pragma unroll
            for (int nb = 0; nb < 4; nb++)
#pragma unroll
                for (int r = 0; r < 4; r++) {
                    xv[nb][r] = (sc[nb][r] + bor[nb][r]) * CS;
                    rmax[r] = fmaxf(rmax[r], xv[nb][r]);
                }
#pragma unroll
            for (int r = 0; r < 4; r++) {
                rmax[r] = fmaxf(rmax[r], __shfl_xor(rmax[r], 1));
                rmax[r] = fmaxf(rmax[r], __shfl_xor(rmax[r], 2));
                rmax[r] = fmaxf(rmax[r], __shfl_xor(rmax[r], 4));
                rmax[r] = fmaxf(rmax[r], __shfl_xor(rmax[r], 8));
            }
            float alpha[4], rsum[4];
#pragma unroll
            for (int r = 0; r < 4; r++) {
                float mn = fmaxf(mst[b][r], rmax[r]);
                alpha[r] = __builtin_amdgcn_exp2f(mst[b][r] - mn);
                mst[b][r] = mn;
                rsum[r] = 0.f;
            }
            // exp + P->LDS fused (each wave writes/reads ONLY its own rows)
#pragma unroll
            for (int nb = 0; nb < 4; nb++)
#pragma unroll
                for (int r = 0; r < 4; r++) {
                    float e = __builtin_amdgcn_exp2f(xv[nb][r] - mst[b][r]);
                    rsum[r] += e;
                    Ps[(w * 16 + quad * 4 + r) * 72 + nb * 16 + l] =
                        __float2bfloat16(e);
                }
#pragma unroll
            for (int r = 0; r < 4; r++) {
                rsum[r] += __shfl_xor(rsum[r], 1);
                rsum[r] += __shfl_xor(rsum[r], 2);
                rsum[r] += __shfl_xor(rsum[r], 4);
                rsum[r] += __shfl_xor(rsum[r], 8);
                lst[b][r] = lst[b][r] * alpha[r] + rsum[r];
            }
#pragma unroll
            for (int nb = 0; nb < 4; nb++)
#pragma unroll
                for (int r = 0; r < 4; r++) oacc[b][nb][r] *= alpha[r];
            // O += P V
            __builtin_amdgcn_s_setprio(1);
#pragma unroll
            for (int ks = 0; ks < 2; ks++) {
                bf16x8 pf = *(const bf16x8*)(Ps + (w * 16 + l) * 72 + ks * 32 + quad * 8);
#pragma unroll
                for (int nb = 0; nb < 4; nb++) {
                    bf16x8 vf = *(const bf16x8*)(Vs[b] + (nb * 16 + l) * 72 + ks * 32 + quad * 8);
                    oacc[b][nb] = mfma16x16(pf, vf, oacc[b][nb]);
                }
            }
            __builtin_amdgcn_s_setprio(0);
        }
    }

    // epilogue: Om[b*4096+q][h*64+d] = O/l  (bf16, merged-head layout)
#pragma unroll
    for (int b = 0; b < 2; b++)
#pragma unroll
        for (int nb = 0; nb < 4; nb++)
#pragma unroll
            for (int r = 0; r < 4; r++) {
                int qq = q0 + w * 16 + quad * 4 + r;
                float val = oacc[b][nb][r] / lst[b][r];
                Om[((size_t)(b * 4096 + qq)) * 512 + h * 64 + nb * 16 + l] =
                    __float2bfloat16(val);
            }
}

// ---------------- output projection ----------------
__global__ __launch_bounds__(256, 4) void out_gemm(
    const __hip_bfloat16* __restrict__ Om, const __hip_bfloat16* __restrict__ wob,
    const float* __restrict__ bo, float* __restrict__ out)
{
    __shared__ __align__(16) __hip_bfloat16 As[128 * 40];
    __shared__ __align__(16) __hip_bfloat16 Bs[64 * 40];
    const int mbase = blockIdx.x * 128, nbase = blockIdx.y * 64;
    f32x4 acc[2][4];
    gemm_core(Om, wob, mbase, nbase, As, Bs, acc);

    const int tid = threadIdx.x;
    const int w = tid >> 6, lane = tid & 63, l = lane & 15, quad = lane >> 4;
#pragma unroll
    for (int mb = 0; mb < 2; mb++)
#pragma unroll
        for (int nb = 0; nb < 4; nb++)
#pragma unroll
            for (int r = 0; r < 4; r++) {
                int m = mbase + w * 32 + mb * 16 + quad * 4 + r;
                int n = nbase + nb * 16 + l;
                out[(size_t)m * EMB + n] = acc[mb][nb][r] + bo[n];
            }
}

extern "C" void kernel_launch(void* const* d_in, const int* in_sizes, int n_in,
                              void* d_out, int out_size, void* d_ws, size_t ws_size,
                              hipStream_t stream) {
    const float* x    = (const float*)d_in[0];
    const float* bias = (const float*)d_in[1];
    const int*   mask = (const int*)d_in[2];
    const float* Wq   = (const float*)d_in[3];
    const float* bq   = (const float*)d_in[4];
    const float* Wk   = (const float*)d_in[5];
    const float* bk   = (const float*)d_in[6];
    const float* Wv   = (const float*)d_in[7];
    const float* bv   = (const float*)d_in[8];
    const float* Wo   = (const float*)d_in[9];
    const float* bo   = (const float*)d_in[10];
    float* out = (float*)d_out;

    char* ws = (char*)d_ws;
    __hip_bfloat16* xb   = (__hip_bfloat16*)ws; ws += (size_t)NROW * EMB * 2;
    __hip_bfloat16* wqkv = (__hip_bfloat16*)ws; ws += (size_t)3 * EMB * EMB * 2;
    __hip_bfloat16* wob  = (__hip_bfloat16*)ws; ws += (size_t)EMB * EMB * 2;
    __hip_bfloat16* Qh   = (__hip_bfloat16*)ws; ws += (size_t)NROW * EMB * 2;
    __hip_bfloat16* Kh   = (__hip_bfloat16*)ws; ws += (size_t)NROW * EMB * 2;
    __hip_bfloat16* Vt   = (__hip_bfloat16*)ws; ws += (size_t)NROW * EMB * 2;
    __hip_bfloat16* Om   = (__hip_bfloat16*)ws; ws += (size_t)NROW * EMB * 2;

    // 1) fp32 -> bf16 conversions (exactly covers NX + 4*NW elements)
    convert_kernel<<<dim3(20480), dim3(256), 0, stream>>>(
        x, Wq, Wk, Wv, Wo, xb, wqkv, wob);
    // 2) fused QKV projection: M=8192, N=1536, K=512
    qkv_gemm<<<dim3(64, 24), dim3(256), 0, stream>>>(
        xb, wqkv, bq, bk, bv, Qh, Kh, Vt);
    // 3) flash attention: grid (H, qt) so blkid%8 == h (XCD L2 locality)
    attn_kernel<<<dim3(NHEAD, 64), dim3(256), 0, stream>>>(
        Qh, Kh, Vt, bias, mask, Om);
    // 4) output projection: M=8192, N=512, K=512
    out_gemm<<<dim3(64, 8), dim3(256), 0, stream>>>(Om, wob, bo, out);
}

// Round 2
// 1178.561 us; speedup vs baseline: 1.1165x; 1.0702x over previous
//
#include <hip/hip_runtime.h>
#include <hip/hip_bf16.h>

typedef __bf16 bf16x8 __attribute__((ext_vector_type(8)));
typedef float f32x4 __attribute__((ext_vector_type(4)));

#define S_LEN 4096
#define EMB   512
#define NHEAD 8
#define HDIM  64
#define NBAT  2
#define NROW  (NBAT * S_LEN)   // 8192

static __device__ __forceinline__ f32x4 mfma16x16(bf16x8 a, bf16x8 b, f32x4 c) {
    return __builtin_amdgcn_mfma_f32_16x16x32_bf16(a, b, c, 0, 0, 0);
}

// ---------------- convert fp32 -> bf16 ----------------
__global__ __launch_bounds__(256) void convert_kernel(
    const float* __restrict__ x, const float* __restrict__ Wq,
    const float* __restrict__ Wk, const float* __restrict__ Wv,
    const float* __restrict__ Wo,
    __hip_bfloat16* __restrict__ xb, __hip_bfloat16* __restrict__ wqkv,
    __hip_bfloat16* __restrict__ wob)
{
    const int NX = NROW * EMB;     // 4194304
    const int NW = EMB * EMB;      // 262144 = 2^18
    int i = blockIdx.x * 256 + threadIdx.x;
    if (i < NX) { xb[i] = __float2bfloat16(x[i]); return; }
    int j = i - NX;
    if (j < 3 * NW) {
        int p = j >> 18, r = j & (NW - 1);
        const float* src = (p == 0) ? Wq : (p == 1) ? Wk : Wv;
        wqkv[j] = __float2bfloat16(src[r]);
    } else if (j < 4 * NW) {
        int r = j - 3 * NW;
        wob[r] = __float2bfloat16(Wo[r]);
    }
}

// ---------------- shared GEMM mainloop ----------------
__device__ __forceinline__ void gemm_core(
    const __hip_bfloat16* __restrict__ A, const __hip_bfloat16* __restrict__ Bw,
    int mbase, int nbase,
    __hip_bfloat16* As, __hip_bfloat16* Bs, f32x4 acc[2][4])
{
    const int tid = threadIdx.x;
    const int w = tid >> 6, lane = tid & 63, l = lane & 15, quad = lane >> 4;
    const f32x4 zero = {0.f, 0.f, 0.f, 0.f};
#pragma unroll
    for (int mb = 0; mb < 2; mb++)
#pragma unroll
        for (int nb = 0; nb < 4; nb++) acc[mb][nb] = zero;

    const int r0 = tid >> 2, kc = tid & 3;
    const __hip_bfloat16* pa0 = A + (size_t)(mbase + r0) * EMB + kc * 8;
    const __hip_bfloat16* pa1 = pa0 + (size_t)64 * EMB;
    const __hip_bfloat16* pb  = Bw + (size_t)(nbase + r0) * EMB + kc * 8;

    uint4 va0 = *(const uint4*)pa0;
    uint4 va1 = *(const uint4*)pa1;
    uint4 vb  = *(const uint4*)pb;

    for (int k0 = 0; k0 < EMB; k0 += 32) {
        __syncthreads();
        *(uint4*)(As + r0 * 40 + kc * 8)        = va0;
        *(uint4*)(As + (r0 + 64) * 40 + kc * 8) = va1;
        *(uint4*)(Bs + r0 * 40 + kc * 8)        = vb;
        __syncthreads();
        if (k0 + 32 < EMB) {
            va0 = *(const uint4*)(pa0 + k0 + 32);
            va1 = *(const uint4*)(pa1 + k0 + 32);
            vb  = *(const uint4*)(pb  + k0 + 32);
        }
        bf16x8 af[2], bfr[4];
#pragma unroll
        for (int mb = 0; mb < 2; mb++)
            af[mb] = *(const bf16x8*)(As + (w * 32 + mb * 16 + l) * 40 + quad * 8);
#pragma unroll
        for (int nb = 0; nb < 4; nb++)
            bfr[nb] = *(const bf16x8*)(Bs + (nb * 16 + l) * 40 + quad * 8);
        __builtin_amdgcn_s_setprio(1);
#pragma unroll
        for (int mb = 0; mb < 2; mb++)
#pragma unroll
            for (int nb = 0; nb < 4; nb++)
                acc[mb][nb] = mfma16x16(af[mb], bfr[nb], acc[mb][nb]);
        __builtin_amdgcn_s_setprio(0);
    }
}

// ---------------- QKV projection ----------------
__global__ __launch_bounds__(256, 4) void qkv_gemm(
    const __hip_bfloat16* __restrict__ xb, const __hip_bfloat16* __restrict__ wqkv,
    const float* __restrict__ bq, const float* __restrict__ bk, const float* __restrict__ bv,
    __hip_bfloat16* __restrict__ Qh, __hip_bfloat16* __restrict__ Kh,
    __hip_bfloat16* __restrict__ Vt)
{
    __shared__ __align__(16) __hip_bfloat16 As[128 * 40];
    __shared__ __align__(16) __hip_bfloat16 Bs[64 * 40];
    const int mbase = blockIdx.x * 128, nbase = blockIdx.y * 64;
    f32x4 acc[2][4];
    gemm_core(xb, wqkv, mbase, nbase, As, Bs, acc);

    const int tid = threadIdx.x;
    const int w = tid >> 6, lane = tid & 63, l = lane & 15, quad = lane >> 4;
    const int p = nbase >> 9;  // uniform per block: 0=Q,1=K,2=V
    const float* bias = (p == 0) ? bq : (p == 1) ? bk : bv;
    __hip_bfloat16* dst = (p == 0) ? Qh : (p == 1) ? Kh : Vt;
#pragma unroll
    for (int mb = 0; mb < 2; mb++)
#pragma unroll
        for (int nb = 0; nb < 4; nb++)
#pragma unroll
            for (int r = 0; r < 4; r++) {
                int m = mbase + w * 32 + mb * 16 + quad * 4 + r;
                int n = nbase + nb * 16 + l;
                int o = n & 511;
                float v = acc[mb][nb][r] + bias[o];
                int b = m >> 12, s = m & 4095, hh = o >> 6, d = o & 63;
                size_t idx = (p == 2)
                    ? ((size_t)((hh * 2 + b) * 64 + d)) * 4096 + s
                    : ((size_t)((hh * 2 + b) * 4096 + s)) * 64 + d;
                dst[idx] = __float2bfloat16(v);
            }
}

// ---------------- flash attention ----------------
// Grid (H, qt): blkid%8 == h -> per-head K/V working set stays in one XCD L2.
// Per kt iter: 16 coalesced 16B loads/thread (8 KV + 4 bias + 4 mask),
// prefetched one iteration ahead into registers. bias+mask fused to an fp32
// Bor LDS tile (pre-masked, pre-scaled) at stage time. All LDS stores go
// through compile-time __shared__ array expressions (ds_write, not flat).
__global__ __launch_bounds__(256, 2) void attn_kernel(
    const __hip_bfloat16* __restrict__ Qh, const __hip_bfloat16* __restrict__ Kh,
    const __hip_bfloat16* __restrict__ Vt,
    const float* __restrict__ bias, const int* __restrict__ mask,
    __hip_bfloat16* __restrict__ Om)
{
    const int h = blockIdx.x, qt = blockIdx.y;
    const int tid = threadIdx.x;
    const int w = tid >> 6, lane = tid & 63, l = lane & 15, quad = lane >> 4;
    const int q0 = qt * 64;
    const float CS = 0.18033688011112042f;  // (1/8) * log2(e)

    __shared__ __align__(16) __hip_bfloat16 Ks[2][64 * 72];
    __shared__ __align__(16) __hip_bfloat16 Vs[2][64 * 72];
    __shared__ __align__(16) __hip_bfloat16 Ps[64 * 72];
    __shared__ __align__(16) float Bor[64 * 68];  // mask?bias*CS:-1e30

    // Q fragments (A-layout): row = q0 + w*16 + l, k = ks*32 + quad*8 + j
    bf16x8 qf[2][2];
#pragma unroll
    for (int b = 0; b < 2; b++) {
        const __hip_bfloat16* qp =
            Qh + ((size_t)((h * 2 + b) * 4096 + q0 + w * 16 + l)) * 64;
        qf[b][0] = *(const bf16x8*)(qp + quad * 8);
        qf[b][1] = *(const bf16x8*)(qp + 32 + quad * 8);
    }

    f32x4 oacc[2][4];
    float mst[2][4], lst[2][4];
    const f32x4 zero = {0.f, 0.f, 0.f, 0.f};
#pragma unroll
    for (int b = 0; b < 2; b++) {
#pragma unroll
        for (int nb = 0; nb < 4; nb++) oacc[b][nb] = zero;
#pragma unroll
        for (int r = 0; r < 4; r++) { mst[b][r] = -__builtin_inff(); lst[b][r] = 0.f; }
    }

    // ---- staging geometry (element offsets, static-indexed int arrays) ----
    const int krow = tid >> 3, kch = tid & 7;        // KV: 32 rows x 8 chunks
    const int ldso0 = krow * 72 + kch * 8;           // j even
    const int ldso1 = ldso0 + 32 * 72;               // j odd
    int koff[8];   // K tiles advance by k0*64, V tiles by k0
#pragma unroll
    for (int j = 0; j < 8; j++) {
        int b = (j >> 1) & 1, isV = j >> 2;
        int row = (j & 1) * 32 + krow;
        koff[j] = isV
            ? ((h * 2 + b) * 64 + row) * 4096 + kch * 8
            : ((h * 2 + b) * 4096 + row) * 64 + kch * 8;
    }
    const float* biasH = bias + (size_t)h * S_LEN * S_LEN;
    int bmo[4], bro[4];   // bias/mask: 64 rows x 16 float4-chunks
#pragma unroll
    for (int j = 0; j < 4; j++) {
        int d = j * 256 + tid, row = d >> 4, c4 = d & 15;
        bmo[j] = (q0 + row) * S_LEN + c4 * 4;  // advance by k0
        bro[j] = row * 68 + c4 * 4;
    }

    uint4  kv[8];
    float4 bv4[4];
    int4   mv4[4];
    // ---- prologue: prefetch kt = 0 ----
#pragma unroll
    for (int j = 0; j < 8; j++)
        kv[j] = (j >> 2) ? *(const uint4*)(Vt + koff[j])
                         : *(const uint4*)(Kh + koff[j]);
#pragma unroll
    for (int j = 0; j < 4; j++) {
        bv4[j] = *(const float4*)(biasH + bmo[j]);
        mv4[j] = *(const int4*)(mask + bmo[j]);
    }

    for (int kt = 0; kt < 64; kt++) {
        __syncthreads();  // prev-iter LDS readers done
        // regs -> LDS (pure ds_write through shared-typed expressions)
#pragma unroll
        for (int j = 0; j < 8; j++) {
            int lo = (j & 1) ? ldso1 : ldso0;
            if (j >> 2) *(uint4*)(Vs[(j >> 1) & 1] + lo) = kv[j];
            else        *(uint4*)(Ks[(j >> 1) & 1] + lo) = kv[j];
        }
#pragma unroll
        for (int j = 0; j < 4; j++) {
            float4 t;
            t.x = mv4[j].x ? bv4[j].x * CS : -1e30f;
            t.y = mv4[j].y ? bv4[j].y * CS : -1e30f;
            t.z = mv4[j].z ? bv4[j].z * CS : -1e30f;
            t.w = mv4[j].w ? bv4[j].w * CS : -1e30f;
            *(float4*)(Bor + bro[j]) = t;
        }
        __syncthreads();

        // ---- issue next-iter prefetch; stays in flight through compute ----
        if (kt < 63) {
            const int k0 = (kt + 1) * 64;
#pragma unroll
            for (int j = 0; j < 8; j++)
                kv[j] = (j >> 2) ? *(const uint4*)(Vt + koff[j] + k0)
                                 : *(const uint4*)(Kh + koff[j] + k0 * 64);
#pragma unroll
            for (int j = 0; j < 4; j++) {
                bv4[j] = *(const float4*)(biasH + bmo[j] + k0);
                mv4[j] = *(const int4*)(mask + bmo[j] + k0);
            }
        }

        // bor fragments: read once, shared by both batches (2-way LDS = free)
        float borr[4][4];
#pragma unroll
        for (int nb = 0; nb < 4; nb++)
#pragma unroll
            for (int r = 0; r < 4; r++)
                borr[nb][r] = Bor[(w * 16 + quad * 4 + r) * 68 + nb * 16 + l];

#pragma unroll
        for (int b = 0; b < 2; b++) {
            // S = Q K^T
            f32x4 sc[4] = {zero, zero, zero, zero};
            __builtin_amdgcn_s_setprio(1);
#pragma unroll
            for (int ks = 0; ks < 2; ks++)
#pragma unroll
                for (int nb = 0; nb < 4; nb++) {
                    bf16x8 kf = *(const bf16x8*)(Ks[b] + (nb * 16 + l) * 72 + ks * 32 + quad * 8);
                    sc[nb] = mfma16x16(qf[b][ks], kf, sc[nb]);
                }
            __builtin_amdgcn_s_setprio(0);
            // online softmax in exp2 domain: xv = sc*CS + bor
            float xv[4][4], rmax[4];
#pragma unroll
            for (int r = 0; r < 4; r++) rmax[r] = -__builtin_inff();
#pragma unroll
            for (int nb = 0; nb < 4; nb++)
#pragma unroll
                for (int r = 0; r < 4; r++) {
                    xv[nb][r] = fmaf(sc[nb][r], CS, borr[nb][r]);
                    rmax[r] = fmaxf(rmax[r], xv[nb][r]);
                }
#pragma unroll
            for (int r = 0; r < 4; r++) {
                rmax[r] = fmaxf(rmax[r], __shfl_xor(rmax[r], 1));
                rmax[r] = fmaxf(rmax[r], __shfl_xor(rmax[r], 2));
                rmax[r] = fmaxf(rmax[r], __shfl_xor(rmax[r], 4));
                rmax[r] = fmaxf(rmax[r], __shfl_xor(rmax[r], 8));
            }
            float alpha[4], rsum[4];
#pragma unroll
            for (int r = 0; r < 4; r++) {
                float mn = fmaxf(mst[b][r], rmax[r]);
                alpha[r] = __builtin_amdgcn_exp2f(mst[b][r] - mn);
                mst[b][r] = mn;
                rsum[r] = 0.f;
            }
            // exp + P->LDS fused (each wave touches ONLY its own 16 rows)
#pragma unroll
            for (int nb = 0; nb < 4; nb++)
#pragma unroll
                for (int r = 0; r < 4; r++) {
                    float e = __builtin_amdgcn_exp2f(xv[nb][r] - mst[b][r]);
                    rsum[r] += e;
                    Ps[(w * 16 + quad * 4 + r) * 72 + nb * 16 + l] =
                        __float2bfloat16(e);
                }
#pragma unroll
            for (int r = 0; r < 4; r++) {
                rsum[r] += __shfl_xor(rsum[r], 1);
                rsum[r] += __shfl_xor(rsum[r], 2);
                rsum[r] += __shfl_xor(rsum[r], 4);
                rsum[r] += __shfl_xor(rsum[r], 8);
                lst[b][r] = lst[b][r] * alpha[r] + rsum[r];
            }
#pragma unroll
            for (int nb = 0; nb < 4; nb++)
#pragma unroll
                for (int r = 0; r < 4; r++) oacc[b][nb][r] *= alpha[r];
            // O += P V
            __builtin_amdgcn_s_setprio(1);
#pragma unroll
            for (int ks = 0; ks < 2; ks++) {
                bf16x8 pf = *(const bf16x8*)(Ps + (w * 16 + l) * 72 + ks * 32 + quad * 8);
#pragma unroll
                for (int nb = 0; nb < 4; nb++) {
                    bf16x8 vf = *(const bf16x8*)(Vs[b] + (nb * 16 + l) * 72 + ks * 32 + quad * 8);
                    oacc[b][nb] = mfma16x16(pf, vf, oacc[b][nb]);
                }
            }
            __builtin_amdgcn_s_setprio(0);
        }
    }

    // epilogue: Om[b*4096+q][h*64+d] = O/l  (bf16, merged-head layout)
#pragma unroll
    for (int b = 0; b < 2; b++)
#pragma unroll
        for (int nb = 0; nb < 4; nb++)
#pragma unroll
            for (int r = 0; r < 4; r++) {
                int qq = q0 + w * 16 + quad * 4 + r;
                float val = oacc[b][nb][r] / lst[b][r];
                Om[((size_t)(b * 4096 + qq)) * 512 + h * 64 + nb * 16 + l] =
                    __float2bfloat16(val);
            }
}

// ---------------- output projection ----------------
__global__ __launch_bounds__(256, 4) void out_gemm(
    const __hip_bfloat16* __restrict__ Om, const __hip_bfloat16* __restrict__ wob,
    const float* __restrict__ bo, float* __restrict__ out)
{
    __shared__ __align__(16) __hip_bfloat16 As[128 * 40];
    __shared__ __align__(16) __hip_bfloat16 Bs[64 * 40];
    const int mbase = blockIdx.x * 128, nbase = blockIdx.y * 64;
    f32x4 acc[2][4];
    gemm_core(Om, wob, mbase, nbase, As, Bs, acc);

    const int tid = threadIdx.x;
    const int w = tid >> 6, lane = tid & 63, l = lane & 15, quad = lane >> 4;
#pragma unroll
    for (int mb = 0; mb < 2; mb++)
#pragma unroll
        for (int nb = 0; nb < 4; nb++)
#pragma unroll
            for (int r = 0; r < 4; r++) {
                int m = mbase + w * 32 + mb * 16 + quad * 4 + r;
                int n = nbase + nb * 16 + l;
                out[(size_t)m * EMB + n] = acc[mb][nb][r] + bo[n];
            }
}

extern "C" void kernel_launch(void* const* d_in, const int* in_sizes, int n_in,
                              void* d_out, int out_size, void* d_ws, size_t ws_size,
                              hipStream_t stream) {
    const float* x    = (const float*)d_in[0];
    const float* bias = (const float*)d_in[1];
    const int*   mask = (const int*)d_in[2];
    const float* Wq   = (const float*)d_in[3];
    const float* bq   = (const float*)d_in[4];
    const float* Wk   = (const float*)d_in[5];
    const float* bk   = (const float*)d_in[6];
    const float* Wv   = (const float*)d_in[7];
    const float* bv   = (const float*)d_in[8];
    const float* Wo   = (const float*)d_in[9];
    const float* bo   = (const float*)d_in[10];
    float* out = (float*)d_out;

    char* ws = (char*)d_ws;
    __hip_bfloat16* xb   = (__hip_bfloat16*)ws; ws += (size_t)NROW * EMB * 2;
    __hip_bfloat16* wqkv = (__hip_bfloat16*)ws; ws += (size_t)3 * EMB * EMB * 2;
    __hip_bfloat16* wob  = (__hip_bfloat16*)ws; ws += (size_t)EMB * EMB * 2;
    __hip_bfloat16* Qh   = (__hip_bfloat16*)ws; ws += (size_t)NROW * EMB * 2;
    __hip_bfloat16* Kh   = (__hip_bfloat16*)ws; ws += (size_t)NROW * EMB * 2;
    __hip_bfloat16* Vt   = (__hip_bfloat16*)ws; ws += (size_t)NROW * EMB * 2;
    __hip_bfloat16* Om   = (__hip_bfloat16*)ws; ws += (size_t)NROW * EMB * 2;

    convert_kernel<<<dim3(20480), dim3(256), 0, stream>>>(
        x, Wq, Wk, Wv, Wo, xb, wqkv, wob);
    qkv_gemm<<<dim3(64, 24), dim3(256), 0, stream>>>(
        xb, wqkv, bq, bk, bv, Qh, Kh, Vt);
    attn_kernel<<<dim3(NHEAD, 64), dim3(256), 0, stream>>>(
        Qh, Kh, Vt, bias, mask, Om);
    out_gemm<<<dim3(64, 8), dim3(256), 0, stream>>>(Om, wob, bo, out);
}

// Round 3
// 1111.578 us; speedup vs baseline: 1.1838x; 1.0603x over previous
//
#include <hip/hip_runtime.h>
#include <hip/hip_bf16.h>

typedef __bf16 bf16x8 __attribute__((ext_vector_type(8)));
typedef float f32x4 __attribute__((ext_vector_type(4)));
typedef _Float16 f16x4 __attribute__((ext_vector_type(4)));

#define S_LEN 4096
#define EMB   512
#define NHEAD 8
#define HDIM  64
#define NBAT  2
#define NROW  (NBAT * S_LEN)   // 8192

static __device__ __forceinline__ f32x4 mfma16x16(bf16x8 a, bf16x8 b, f32x4 c) {
    return __builtin_amdgcn_mfma_f32_16x16x32_bf16(a, b, c, 0, 0, 0);
}

// async global -> LDS, 16B per lane. LDS dest must be wave-uniform; HW appends
// lane*16. Global src is per-lane.
typedef __attribute__((address_space(1))) const void gas_void;
typedef __attribute__((address_space(3))) void las_void;
static __device__ __forceinline__ void gl16(const void* g, void* l) {
    __builtin_amdgcn_global_load_lds((gas_void*)g, (las_void*)l, 16, 0, 0);
}

// ---------------- convert fp32 -> bf16 ----------------
__global__ __launch_bounds__(256) void convert_kernel(
    const float* __restrict__ x, const float* __restrict__ Wq,
    const float* __restrict__ Wk, const float* __restrict__ Wv,
    const float* __restrict__ Wo,
    __hip_bfloat16* __restrict__ xb, __hip_bfloat16* __restrict__ wqkv,
    __hip_bfloat16* __restrict__ wob)
{
    const int NX = NROW * EMB;     // 4194304
    const int NW = EMB * EMB;      // 262144 = 2^18
    int i = blockIdx.x * 256 + threadIdx.x;
    if (i < NX) { xb[i] = __float2bfloat16(x[i]); return; }
    int j = i - NX;
    if (j < 3 * NW) {
        int p = j >> 18, r = j & (NW - 1);
        const float* src = (p == 0) ? Wq : (p == 1) ? Wk : Wv;
        wqkv[j] = __float2bfloat16(src[r]);
    } else if (j < 4 * NW) {
        int r = j - 3 * NW;
        wob[r] = __float2bfloat16(Wo[r]);
    }
}

// ---------------- merged bias prep ----------------
// Bm[h][qt][kt][row][col'] fp16 = mask ? bias*CS : -60000, tiled 64x64 per
// (qt,kt), col' = swizzle so attn's per-quad reads are bank-conflict-free:
// col' = (col&15) | (((col>>4) ^ ((row>>2)&3)) << 4)
__global__ __launch_bounds__(256) void prep_kernel(
    const float* __restrict__ bias, const int* __restrict__ mask,
    _Float16* __restrict__ Bm)
{
    const float CS = 0.18033688011112042f;  // (1/8)*log2(e)
    int i = blockIdx.x * 256 + threadIdx.x;     // 33,554,432 k4-chunks
    int h = i >> 22;
    int rem = i & ((1 << 22) - 1);
    int q = rem >> 10;
    int k = (rem & 1023) << 2;
    float4 b4 = *(const float4*)(bias + ((size_t)h * S_LEN + q) * S_LEN + k);
    int4   m4 = *(const int4*)(mask + (size_t)q * S_LEN + k);
    int row = q & 63, kcol = k & 63;
    int colp = (kcol & 15) | ((((kcol >> 4) ^ ((row >> 2) & 3)) & 3) << 4);
    size_t dst = ((size_t)((h * 64 + (q >> 6)) * 64 + (k >> 6))) * 4096
               + row * 64 + colp;
    f16x4 o;
    o[0] = (_Float16)(m4.x ? b4.x * CS : -60000.f);
    o[1] = (_Float16)(m4.y ? b4.y * CS : -60000.f);
    o[2] = (_Float16)(m4.z ? b4.z * CS : -60000.f);
    o[3] = (_Float16)(m4.w ? b4.w * CS : -60000.f);
    *(f16x4*)(Bm + dst) = o;
}

// ---------------- shared GEMM mainloop ----------------
__device__ __forceinline__ void gemm_core(
    const __hip_bfloat16* __restrict__ A, const __hip_bfloat16* __restrict__ Bw,
    int mbase, int nbase,
    __hip_bfloat16* As, __hip_bfloat16* Bs, f32x4 acc[2][4])
{
    const int tid = threadIdx.x;
    const int w = tid >> 6, lane = tid & 63, l = lane & 15, quad = lane >> 4;
    const f32x4 zero = {0.f, 0.f, 0.f, 0.f};
#pragma unroll
    for (int mb = 0; mb < 2; mb++)
#pragma unroll
        for (int nb = 0; nb < 4; nb++) acc[mb][nb] = zero;

    const int r0 = tid >> 2, kc = tid & 3;
    const __hip_bfloat16* pa0 = A + (size_t)(mbase + r0) * EMB + kc * 8;
    const __hip_bfloat16* pa1 = pa0 + (size_t)64 * EMB;
    const __hip_bfloat16* pb  = Bw + (size_t)(nbase + r0) * EMB + kc * 8;

    uint4 va0 = *(const uint4*)pa0;
    uint4 va1 = *(const uint4*)pa1;
    uint4 vb  = *(const uint4*)pb;

    for (int k0 = 0; k0 < EMB; k0 += 32) {
        __syncthreads();
        *(uint4*)(As + r0 * 40 + kc * 8)        = va0;
        *(uint4*)(As + (r0 + 64) * 40 + kc * 8) = va1;
        *(uint4*)(Bs + r0 * 40 + kc * 8)        = vb;
        __syncthreads();
        if (k0 + 32 < EMB) {
            va0 = *(const uint4*)(pa0 + k0 + 32);
            va1 = *(const uint4*)(pa1 + k0 + 32);
            vb  = *(const uint4*)(pb  + k0 + 32);
        }
        bf16x8 af[2], bfr[4];
#pragma unroll
        for (int mb = 0; mb < 2; mb++)
            af[mb] = *(const bf16x8*)(As + (w * 32 + mb * 16 + l) * 40 + quad * 8);
#pragma unroll
        for (int nb = 0; nb < 4; nb++)
            bfr[nb] = *(const bf16x8*)(Bs + (nb * 16 + l) * 40 + quad * 8);
        __builtin_amdgcn_s_setprio(1);
#pragma unroll
        for (int mb = 0; mb < 2; mb++)
#pragma unroll
            for (int nb = 0; nb < 4; nb++)
                acc[mb][nb] = mfma16x16(af[mb], bfr[nb], acc[mb][nb]);
        __builtin_amdgcn_s_setprio(0);
    }
}

// ---------------- QKV projection ----------------
// V epilogue: LDS-transpose then coalesced 16B stores (the old per-element
// scatter was 2B stores at 8KB stride = 32-64x write amplification).
__global__ __launch_bounds__(256, 4) void qkv_gemm(
    const __hip_bfloat16* __restrict__ xb, const __hip_bfloat16* __restrict__ wqkv,
    const float* __restrict__ bq, const float* __restrict__ bk, const float* __restrict__ bv,
    __hip_bfloat16* __restrict__ Qh, __hip_bfloat16* __restrict__ Kh,
    __hip_bfloat16* __restrict__ Vt)
{
    __shared__ __align__(16) __hip_bfloat16 As[128 * 40];
    __shared__ __align__(16) __hip_bfloat16 Bs[64 * 40];
    __shared__ __align__(16) __hip_bfloat16 Ts[64 * 136];   // V transpose tile
    const int mbase = blockIdx.x * 128, nbase = blockIdx.y * 64;
    f32x4 acc[2][4];
    gemm_core(xb, wqkv, mbase, nbase, As, Bs, acc);

    const int tid = threadIdx.x;
    const int w = tid >> 6, lane = tid & 63, l = lane & 15, quad = lane >> 4;
    const int p = nbase >> 9;  // uniform per block: 0=Q,1=K,2=V
    const float* bias = (p == 0) ? bq : (p == 1) ? bk : bv;

    if (p == 2) {
        // acc -> Ts[d][s_local] (64 x 128, pad 136)
#pragma unroll
        for (int mb = 0; mb < 2; mb++)
#pragma unroll
            for (int nb = 0; nb < 4; nb++)
#pragma unroll
                for (int r = 0; r < 4; r++) {
                    int sl = w * 32 + mb * 16 + quad * 4 + r;
                    int d  = nb * 16 + l;
                    float v = acc[mb][nb][r] + bias[(nbase & 511) + d];
                    Ts[d * 136 + sl] = __float2bfloat16(v);
                }
        __syncthreads();
        const int b = mbase >> 12, s0 = mbase & 4095;
        const int hh = (nbase & 511) >> 6;
#pragma unroll
        for (int c = tid; c < 1024; c += 256) {
            int d = c >> 4, sc = c & 15;
            uint4 v = *(const uint4*)(Ts + d * 136 + sc * 8);
            *(uint4*)(Vt + ((size_t)((hh * 2 + b) * 64 + d)) * 4096 + s0 + sc * 8) = v;
        }
        return;
    }
    __hip_bfloat16* dst = (p == 0) ? Qh : Kh;
#pragma unroll
    for (int mb = 0; mb < 2; mb++)
#pragma unroll
        for (int nb = 0; nb < 4; nb++)
#pragma unroll
            for (int r = 0; r < 4; r++) {
                int m = mbase + w * 32 + mb * 16 + quad * 4 + r;
                int n = nbase + nb * 16 + l;
                int o = n & 511;
                float v = acc[mb][nb][r] + bias[o];
                int b = m >> 12, s = m & 4095, hh = o >> 6, d = o & 63;
                dst[((size_t)((hh * 2 + b) * 4096 + s)) * 64 + d] = __float2bfloat16(v);
            }
}

// ---------------- flash attention (gl_lds async pipeline) ----------------
// LDS (73.2 KB, 2 blocks/CU):
//   Kl[b][64s][64d]      single-buffered in time (refilled after QK(b1))
//   Vl[buf][b][64d][64s] double-buffered
//   BmL[buf][64q][64k']  double-buffered (pre-merged fp16 bias, pre-swizzled)
// All tiles linear with 16B-chunk XOR swizzle: LDS slot = ch ^ (row&7),
// applied on the per-lane GLOBAL source address and again on reads (#21).
// 2 barriers/iter; every gl_lds group gets >=1 compute phase of flight.
__global__ __launch_bounds__(256, 2) void attn_kernel(
    const __hip_bfloat16* __restrict__ Qh, const __hip_bfloat16* __restrict__ Kh,
    const __hip_bfloat16* __restrict__ Vt, const _Float16* __restrict__ Bm,
    __hip_bfloat16* __restrict__ Om)
{
    const int h = blockIdx.x, qt = blockIdx.y;
    const int tid = threadIdx.x;
    const int w = tid >> 6, lane = tid & 63, l = lane & 15, quad = lane >> 4;
    const int q0 = qt * 64;
    const float CS = 0.18033688011112042f;

    __shared__ __align__(16) __hip_bfloat16 Kl[2][4096];
    __shared__ __align__(16) __hip_bfloat16 Vl[2][2][4096];
    __shared__ __align__(16) _Float16      BmL[2][4096];
    __shared__ __align__(16) __hip_bfloat16 Ps[64 * 72];

    // per-lane swizzled source offset patterns (elements)
    const int swz  = ((lane & 7) ^ ((lane >> 3) & 7)) << 3;
    const int kpat = ((lane >> 3) << 6) + swz;          // K: row stride 64
    const int vpat = ((lane >> 3) << 12) + swz;         // V: row stride 4096

    const int wb = w & 1, wi4 = (w >> 1) * 4;           // wave work mapping
    const __hip_bfloat16* Kbase = Kh + ((size_t)((h * 2 + wb) * 4096)) * 64;
    const __hip_bfloat16* Vbase = Vt + ((size_t)((h * 2 + wb) * 64)) * 4096;
    const _Float16*       Bbase = Bm + ((size_t)((h * 64 + qt) * 64)) * 4096;

    // Q fragments: row = q0 + w*16 + l, k = ks*32 + quad*8 + j
    bf16x8 qf[2][2];
#pragma unroll
    for (int b = 0; b < 2; b++) {
        const __hip_bfloat16* qp =
            Qh + ((size_t)((h * 2 + b) * 4096 + q0 + w * 16 + l)) * 64;
        qf[b][0] = *(const bf16x8*)(qp + quad * 8);
        qf[b][1] = *(const bf16x8*)(qp + 32 + quad * 8);
    }

    f32x4 oacc[2][4];
    float mst[2][4], lst[2][4];
    const f32x4 zero = {0.f, 0.f, 0.f, 0.f};
#pragma unroll
    for (int b = 0; b < 2; b++) {
#pragma unroll
        for (int nb = 0; nb < 4; nb++) oacc[b][nb] = zero;
#pragma unroll
        for (int r = 0; r < 4; r++) { mst[b][r] = -__builtin_inff(); lst[b][r] = 0.f; }
    }

    // ---- prologue: async-stage tiles for kt=0 ----
    {
        const __hip_bfloat16* kb = Kbase;          // kt=0
#pragma unroll
        for (int j = 0; j < 4; j++) {
            int i = wi4 + j;
            gl16(kb + i * 512 + kpat, Kl[wb] + i * 512);
        }
        const __hip_bfloat16* vb = Vbase;
#pragma unroll
        for (int j = 0; j < 4; j++) {
            int i = wi4 + j;
            gl16(vb + (size_t)i * 32768 + vpat, Vl[0][wb] + i * 512);
        }
        const _Float16* bb = Bbase;
#pragma unroll
        for (int j = 0; j < 2; j++) {
            int i = w * 2 + j;
            gl16(bb + i * 512 + lane * 8, BmL[0] + i * 512);
        }
    }

    for (int kt = 0; kt < 64; kt++) {
        const int cur = kt & 1, nxt = cur ^ 1;
        __syncthreads();   // B1: Kl(kt) ready; Vl[cur]/BmL[cur] ready

        // issue V(kt+1), Bm(kt+1) -> [nxt]; fly through QK/softmax/PV(b0)+QK(b1)
        if (kt < 63) {
            const __hip_bfloat16* vb = Vbase + (kt + 1) * 64;
#pragma unroll
            for (int j = 0; j < 4; j++) {
                int i = wi4 + j;
                gl16(vb + (size_t)i * 32768 + vpat, Vl[nxt][wb] + i * 512);
            }
            const _Float16* bb = Bbase + (size_t)(kt + 1) * 4096;
#pragma unroll
            for (int j = 0; j < 2; j++) {
                int i = w * 2 + j;
                gl16(bb + i * 512 + lane * 8, BmL[nxt] + i * 512);
            }
        }

        // pre-scaled masked bias fragments, shared by both batches
        float borr[4][4];
#pragma unroll
        for (int nb = 0; nb < 4; nb++)
#pragma unroll
            for (int r = 0; r < 4; r++) {
                int row = w * 16 + quad * 4 + r;
                borr[nb][r] =
                    (float)BmL[cur][row * 64 + (((nb ^ quad) & 3) << 4) + l];
            }

        f32x4 sc1[4] = {zero, zero, zero, zero};
#pragma unroll
        for (int b = 0; b < 2; b++) {
            f32x4 sc[4] = {zero, zero, zero, zero};
            // S = Q K^T  (swizzled chunk reads: 2-way max)
            __builtin_amdgcn_s_setprio(1);
#pragma unroll
            for (int ks = 0; ks < 2; ks++)
#pragma unroll
                for (int nb = 0; nb < 4; nb++) {
                    bf16x8 kf = *(const bf16x8*)(
                        Kl[b] + ((nb * 16 + l) << 6) + (((ks * 4 + quad) ^ (l & 7)) << 3));
                    sc[nb] = mfma16x16(qf[b][ks], kf, sc[nb]);
                }
            __builtin_amdgcn_s_setprio(0);

            if (b == 1) {
#pragma unroll
                for (int nb = 0; nb < 4; nb++) sc1[nb] = sc[nb];
                break;  // finish batch 1 after K-refill barrier
            }
            // ---- softmax + PV for batch 0 ----
            float xv[4][4], rmax[4];
#pragma unroll
            for (int r = 0; r < 4; r++) rmax[r] = -__builtin_inff();
#pragma unroll
            for (int nb = 0; nb < 4; nb++)
#pragma unroll
                for (int r = 0; r < 4; r++) {
                    xv[nb][r] = fmaf(sc[nb][r], CS, borr[nb][r]);
                    rmax[r] = fmaxf(rmax[r], xv[nb][r]);
                }
#pragma unroll
            for (int r = 0; r < 4; r++) {
                rmax[r] = fmaxf(rmax[r], __shfl_xor(rmax[r], 1));
                rmax[r] = fmaxf(rmax[r], __shfl_xor(rmax[r], 2));
                rmax[r] = fmaxf(rmax[r], __shfl_xor(rmax[r], 4));
                rmax[r] = fmaxf(rmax[r], __shfl_xor(rmax[r], 8));
            }
            float alpha[4], rsum[4];
#pragma unroll
            for (int r = 0; r < 4; r++) {
                float mn = fmaxf(mst[0][r], rmax[r]);
                alpha[r] = __builtin_amdgcn_exp2f(mst[0][r] - mn);
                mst[0][r] = mn;
                rsum[r] = 0.f;
            }
#pragma unroll
            for (int nb = 0; nb < 4; nb++)
#pragma unroll
                for (int r = 0; r < 4; r++) {
                    float e = __builtin_amdgcn_exp2f(xv[nb][r] - mst[0][r]);
                    rsum[r] += e;
                    Ps[(w * 16 + quad * 4 + r) * 72 + nb * 16 + l] =
                        __float2bfloat16(e);
                }
#pragma unroll
            for (int r = 0; r < 4; r++) {
                rsum[r] += __shfl_xor(rsum[r], 1);
                rsum[r] += __shfl_xor(rsum[r], 2);
                rsum[r] += __shfl_xor(rsum[r], 4);
                rsum[r] += __shfl_xor(rsum[r], 8);
                lst[0][r] = lst[0][r] * alpha[r] + rsum[r];
            }
#pragma unroll
            for (int nb = 0; nb < 4; nb++)
#pragma unroll
                for (int r = 0; r < 4; r++) oacc[0][nb][r] *= alpha[r];
            __builtin_amdgcn_s_setprio(1);
#pragma unroll
            for (int ks = 0; ks < 2; ks++) {
                bf16x8 pf = *(const bf16x8*)(Ps + (w * 16 + l) * 72 + ks * 32 + quad * 8);
#pragma unroll
                for (int nb = 0; nb < 4; nb++) {
                    bf16x8 vf = *(const bf16x8*)(
                        Vl[cur][0] + ((nb * 16 + l) << 6) + (((ks * 4 + quad) ^ (l & 7)) << 3));
                    oacc[0][nb] = mfma16x16(pf, vf, oacc[0][nb]);
                }
            }
            __builtin_amdgcn_s_setprio(0);
        }

        __syncthreads();   // B2: all waves done with Kl; drains V/Bm(kt+1)
        // refill Kl for kt+1; flies through softmax+PV of batch 1
        if (kt < 63) {
            const __hip_bfloat16* kb = Kbase + (size_t)(kt + 1) * 64 * 64;
#pragma unroll
            for (int j = 0; j < 4; j++) {
                int i = wi4 + j;
                gl16(kb + i * 512 + kpat, Kl[wb] + i * 512);
            }
        }

        // ---- softmax + PV for batch 1 ----
        {
            float xv[4][4], rmax[4];
#pragma unroll
            for (int r = 0; r < 4; r++) rmax[r] = -__builtin_inff();
#pragma unroll
            for (int nb = 0; nb < 4; nb++)
#pragma unroll
                for (int r = 0; r < 4; r++) {
                    xv[nb][r] = fmaf(sc1[nb][r], CS, borr[nb][r]);
                    rmax[r] = fmaxf(rmax[r], xv[nb][r]);
                }
#pragma unroll
            for (int r = 0; r < 4; r++) {
                rmax[r] = fmaxf(rmax[r], __shfl_xor(rmax[r], 1));
                rmax[r] = fmaxf(rmax[r], __shfl_xor(rmax[r], 2));
                rmax[r] = fmaxf(rmax[r], __shfl_xor(rmax[r], 4));
                rmax[r] = fmaxf(rmax[r], __shfl_xor(rmax[r], 8));
            }
            float alpha[4], rsum[4];
#pragma unroll
            for (int r = 0; r < 4; r++) {
                float mn = fmaxf(mst[1][r], rmax[r]);
                alpha[r] = __builtin_amdgcn_exp2f(mst[1][r] - mn);
                mst[1][r] = mn;
                rsum[r] = 0.f;
            }
#pragma unroll
            for (int nb = 0; nb < 4; nb++)
#pragma unroll
                for (int r = 0; r < 4; r++) {
                    float e = __builtin_amdgcn_exp2f(xv[nb][r] - mst[1][r]);
                    rsum[r] += e;
                    Ps[(w * 16 + quad * 4 + r) * 72 + nb * 16 + l] =
                        __float2bfloat16(e);
                }
#pragma unroll
            for (int r = 0; r < 4; r++) {
                rsum[r] += __shfl_xor(rsum[r], 1);
                rsum[r] += __shfl_xor(rsum[r], 2);
                rsum[r] += __shfl_xor(rsum[r], 4);
                rsum[r] += __shfl_xor(rsum[r], 8);
                lst[1][r] = lst[1][r] * alpha[r] + rsum[r];
            }
#pragma unroll
            for (int nb = 0; nb < 4; nb++)
#pragma unroll
                for (int r = 0; r < 4; r++) oacc[1][nb][r] *= alpha[r];
            __builtin_amdgcn_s_setprio(1);
#pragma unroll
            for (int ks = 0; ks < 2; ks++) {
                bf16x8 pf = *(const bf16x8*)(Ps + (w * 16 + l) * 72 + ks * 32 + quad * 8);
#pragma unroll
                for (int nb = 0; nb < 4; nb++) {
                    bf16x8 vf = *(const bf16x8*)(
                        Vl[cur][1] + ((nb * 16 + l) << 6) + (((ks * 4 + quad) ^ (l & 7)) << 3));
                    oacc[1][nb] = mfma16x16(pf, vf, oacc[1][nb]);
                }
            }
            __builtin_amdgcn_s_setprio(0);
        }
    }

    // epilogue
#pragma unroll
    for (int b = 0; b < 2; b++)
#pragma unroll
        for (int nb = 0; nb < 4; nb++)
#pragma unroll
            for (int r = 0; r < 4; r++) {
                int qq = q0 + w * 16 + quad * 4 + r;
                float val = oacc[b][nb][r] / lst[b][r];
                Om[((size_t)(b * 4096 + qq)) * 512 + h * 64 + nb * 16 + l] =
                    __float2bfloat16(val);
            }
}

// ---------------- fallback attention (round-2, used if workspace small) ----
__global__ __launch_bounds__(256, 2) void attn_fallback(
    const __hip_bfloat16* __restrict__ Qh, const __hip_bfloat16* __restrict__ Kh,
    const __hip_bfloat16* __restrict__ Vt,
    const float* __restrict__ bias, const int* __restrict__ mask,
    __hip_bfloat16* __restrict__ Om)
{
    const int h = blockIdx.x, qt = blockIdx.y;
    const int tid = threadIdx.x;
    const int w = tid >> 6, lane = tid & 63, l = lane & 15, quad = lane >> 4;
    const int q0 = qt * 64;
    const float CS = 0.18033688011112042f;

    __shared__ __align__(16) __hip_bfloat16 Ks[2][64 * 72];
    __shared__ __align__(16) __hip_bfloat16 Vs[2][64 * 72];
    __shared__ __align__(16) __hip_bfloat16 Ps[64 * 72];
    __shared__ __align__(16) float Bor[64 * 68];

    bf16x8 qf[2][2];
#pragma unroll
    for (int b = 0; b < 2; b++) {
        const __hip_bfloat16* qp =
            Qh + ((size_t)((h * 2 + b) * 4096 + q0 + w * 16 + l)) * 64;
        qf[b][0] = *(const bf16x8*)(qp + quad * 8);
        qf[b][1] = *(const bf16x8*)(qp + 32 + quad * 8);
    }
    f32x4 oacc[2][4];
    float mst[2][4], lst[2][4];
    const f32x4 zero = {0.f, 0.f, 0.f, 0.f};
#pragma unroll
    for (int b = 0; b < 2; b++) {
#pragma unroll
        for (int nb = 0; nb < 4; nb++) oacc[b][nb] = zero;
#pragma unroll
        for (int r = 0; r < 4; r++) { mst[b][r] = -__builtin_inff(); lst[b][r] = 0.f; }
    }
    const int krow = tid >> 3, kch = tid & 7;
    const int ldso0 = krow * 72 + kch * 8;
    const int ldso1 = ldso0 + 32 * 72;
    int koff[8];
#pragma unroll
    for (int j = 0; j < 8; j++) {
        int b = (j >> 1) & 1, isV = j >> 2;
        int row = (j & 1) * 32 + krow;
        koff[j] = isV
            ? ((h * 2 + b) * 64 + row) * 4096 + kch * 8
            : ((h * 2 + b) * 4096 + row) * 64 + kch * 8;
    }
    const float* biasH = bias + (size_t)h * S_LEN * S_LEN;
    int bmo[4], bro[4];
#pragma unroll
    for (int j = 0; j < 4; j++) {
        int d = j * 256 + tid, row = d >> 4, c4 = d & 15;
        bmo[j] = (q0 + row) * S_LEN + c4 * 4;
        bro[j] = row * 68 + c4 * 4;
    }
    uint4 kv[8]; float4 bv4[4]; int4 mv4[4];
#pragma unroll
    for (int j = 0; j < 8; j++)
        kv[j] = (j >> 2) ? *(const uint4*)(Vt + koff[j]) : *(const uint4*)(Kh + koff[j]);
#pragma unroll
    for (int j = 0; j < 4; j++) {
        bv4[j] = *(const float4*)(biasH + bmo[j]);
        mv4[j] = *(const int4*)(mask + bmo[j]);
    }
    for (int kt = 0; kt < 64; kt++) {
        __syncthreads();
#pragma unroll
        for (int j = 0; j < 8; j++) {
            int lo = (j & 1) ? ldso1 : ldso0;
            if (j >> 2) *(uint4*)(Vs[(j >> 1) & 1] + lo) = kv[j];
            else        *(uint4*)(Ks[(j >> 1) & 1] + lo) = kv[j];
        }
#pragma unroll
        for (int j = 0; j < 4; j++) {
            float4 t;
            t.x = mv4[j].x ? bv4[j].x * CS : -1e30f;
            t.y = mv4[j].y ? bv4[j].y * CS : -1e30f;
            t.z = mv4[j].z ? bv4[j].z * CS : -1e30f;
            t.w = mv4[j].w ? bv4[j].w * CS : -1e30f;
            *(float4*)(Bor + bro[j]) = t;
        }
        __syncthreads();
        if (kt < 63) {
            const int k0 = (kt + 1) * 64;
#pragma unroll
            for (int j = 0; j < 8; j++)
                kv[j] = (j >> 2) ? *(const uint4*)(Vt + koff[j] + k0)
                                 : *(const uint4*)(Kh + koff[j] + k0 * 64);
#pragma unroll
            for (int j = 0; j < 4; j++) {
                bv4[j] = *(const float4*)(biasH + bmo[j] + k0);
                mv4[j] = *(const int4*)(mask + bmo[j] + k0);
            }
        }
        float borr[4][4];
#pragma unroll
        for (int nb = 0; nb < 4; nb++)
#pragma unroll
            for (int r = 0; r < 4; r++)
                borr[nb][r] = Bor[(w * 16 + quad * 4 + r) * 68 + nb * 16 + l];
#pragma unroll
        for (int b = 0; b < 2; b++) {
            f32x4 sc[4] = {zero, zero, zero, zero};
            __builtin_amdgcn_s_setprio(1);
#pragma unroll
            for (int ks = 0; ks < 2; ks++)
#pragma unroll
                for (int nb = 0; nb < 4; nb++) {
                    bf16x8 kf = *(const bf16x8*)(Ks[b] + (nb * 16 + l) * 72 + ks * 32 + quad * 8);
                    sc[nb] = mfma16x16(qf[b][ks], kf, sc[nb]);
                }
            __builtin_amdgcn_s_setprio(0);
            float xv[4][4], rmax[4];
#pragma unroll
            for (int r = 0; r < 4; r++) rmax[r] = -__builtin_inff();
#pragma unroll
            for (int nb = 0; nb < 4; nb++)
#pragma unroll
                for (int r = 0; r < 4; r++) {
                    xv[nb][r] = fmaf(sc[nb][r], CS, borr[nb][r]);
                    rmax[r] = fmaxf(rmax[r], xv[nb][r]);
                }
#pragma unroll
            for (int r = 0; r < 4; r++) {
                rmax[r] = fmaxf(rmax[r], __shfl_xor(rmax[r], 1));
                rmax[r] = fmaxf(rmax[r], __shfl_xor(rmax[r], 2));
                rmax[r] = fmaxf(rmax[r], __shfl_xor(rmax[r], 4));
                rmax[r] = fmaxf(rmax[r], __shfl_xor(rmax[r], 8));
            }
            float alpha[4], rsum[4];
#pragma unroll
            for (int r = 0; r < 4; r++) {
                float mn = fmaxf(mst[b][r], rmax[r]);
                alpha[r] = __builtin_amdgcn_exp2f(mst[b][r] - mn);
                mst[b][r] = mn;
                rsum[r] = 0.f;
            }
#pragma unroll
            for (int nb = 0; nb < 4; nb++)
#pragma unroll
                for (int r = 0; r < 4; r++) {
                    float e = __builtin_amdgcn_exp2f(xv[nb][r] - mst[b][r]);
                    rsum[r] += e;
                    Ps[(w * 16 + quad * 4 + r) * 72 + nb * 16 + l] = __float2bfloat16(e);
                }
#pragma unroll
            for (int r = 0; r < 4; r++) {
                rsum[r] += __shfl_xor(rsum[r], 1);
                rsum[r] += __shfl_xor(rsum[r], 2);
                rsum[r] += __shfl_xor(rsum[r], 4);
                rsum[r] += __shfl_xor(rsum[r], 8);
                lst[b][r] = lst[b][r] * alpha[r] + rsum[r];
            }
#pragma unroll
            for (int nb = 0; nb < 4; nb++)
#pragma unroll
                for (int r = 0; r < 4; r++) oacc[b][nb][r] *= alpha[r];
            __builtin_amdgcn_s_setprio(1);
#pragma unroll
            for (int ks = 0; ks < 2; ks++) {
                bf16x8 pf = *(const bf16x8*)(Ps + (w * 16 + l) * 72 + ks * 32 + quad * 8);
#pragma unroll
                for (int nb = 0; nb < 4; nb++) {
                    bf16x8 vf = *(const bf16x8*)(Vs[b] + (nb * 16 + l) * 72 + ks * 32 + quad * 8);
                    oacc[b][nb] = mfma16x16(pf, vf, oacc[b][nb]);
                }
            }
            __builtin_amdgcn_s_setprio(0);
        }
    }
#pragma unroll
    for (int b = 0; b < 2; b++)
#pragma unroll
        for (int nb = 0; nb < 4; nb++)
#pragma unroll
            for (int r = 0; r < 4; r++) {
                int qq = q0 + w * 16 + quad * 4 + r;
                float val = oacc[b][nb][r] / lst[b][r];
                Om[((size_t)(b * 4096 + qq)) * 512 + h * 64 + nb * 16 + l] =
                    __float2bfloat16(val);
            }
}

// ---------------- output projection ----------------
__global__ __launch_bounds__(256, 4) void out_gemm(
    const __hip_bfloat16* __restrict__ Om, const __hip_bfloat16* __restrict__ wob,
    const float* __restrict__ bo, float* __restrict__ out)
{
    __shared__ __align__(16) __hip_bfloat16 As[128 * 40];
    __shared__ __align__(16) __hip_bfloat16 Bs[64 * 40];
    const int mbase = blockIdx.x * 128, nbase = blockIdx.y * 64;
    f32x4 acc[2][4];
    gemm_core(Om, wob, mbase, nbase, As, Bs, acc);

    const int tid = threadIdx.x;
    const int w = tid >> 6, lane = tid & 63, l = lane & 15, quad = lane >> 4;
#pragma unroll
    for (int mb = 0; mb < 2; mb++)
#pragma unroll
        for (int nb = 0; nb < 4; nb++)
#pragma unroll
            for (int r = 0; r < 4; r++) {
                int m = mbase + w * 32 + mb * 16 + quad * 4 + r;
                int n = nbase + nb * 16 + l;
                out[(size_t)m * EMB + n] = acc[mb][nb][r] + bo[n];
            }
}

extern "C" void kernel_launch(void* const* d_in, const int* in_sizes, int n_in,
                              void* d_out, int out_size, void* d_ws, size_t ws_size,
                              hipStream_t stream) {
    const float* x    = (const float*)d_in[0];
    const float* bias = (const float*)d_in[1];
    const int*   mask = (const int*)d_in[2];
    const float* Wq   = (const float*)d_in[3];
    const float* bq   = (const float*)d_in[4];
    const float* Wk   = (const float*)d_in[5];
    const float* bk   = (const float*)d_in[6];
    const float* Wv   = (const float*)d_in[7];
    const float* bv   = (const float*)d_in[8];
    const float* Wo   = (const float*)d_in[9];
    const float* bo   = (const float*)d_in[10];
    float* out = (float*)d_out;

    char* ws = (char*)d_ws;
    size_t off = 0;
    __hip_bfloat16* xb   = (__hip_bfloat16*)(ws + off); off += (size_t)NROW * EMB * 2;
    __hip_bfloat16* wqkv = (__hip_bfloat16*)(ws + off); off += (size_t)3 * EMB * EMB * 2;
    __hip_bfloat16* wob  = (__hip_bfloat16*)(ws + off); off += (size_t)EMB * EMB * 2;
    __hip_bfloat16* Qh   = (__hip_bfloat16*)(ws + off); off += (size_t)NROW * EMB * 2;
    __hip_bfloat16* Kh   = (__hip_bfloat16*)(ws + off); off += (size_t)NROW * EMB * 2;
    __hip_bfloat16* Vt   = (__hip_bfloat16*)(ws + off); off += (size_t)NROW * EMB * 2;
    __hip_bfloat16* Om   = (__hip_bfloat16*)(ws + off); off += (size_t)NROW * EMB * 2;
    _Float16*       Bm   = (_Float16*)(ws + off);
    const size_t BMBYTES = (size_t)NHEAD * S_LEN * S_LEN * 2;  // 256 MB
    const bool bmok = ws_size >= off + BMBYTES;

    convert_kernel<<<dim3(20480), dim3(256), 0, stream>>>(
        x, Wq, Wk, Wv, Wo, xb, wqkv, wob);
    qkv_gemm<<<dim3(64, 24), dim3(256), 0, stream>>>(
        xb, wqkv, bq, bk, bv, Qh, Kh, Vt);
    if (bmok) {
        prep_kernel<<<dim3(131072), dim3(256), 0, stream>>>(bias, mask, Bm);
        attn_kernel<<<dim3(NHEAD, 64), dim3(256), 0, stream>>>(
            Qh, Kh, Vt, Bm, Om);
    } else {
        attn_fallback<<<dim3(NHEAD, 64), dim3(256), 0, stream>>>(
            Qh, Kh, Vt, bias, mask, Om);
    }
    out_gemm<<<dim3(64, 8), dim3(256), 0, stream>>>(Om, wob, bo, out);
}